// Round 1
// baseline (2437.502 us; speedup 1.0000x reference)
//
#include <hip/hip_runtime.h>
#include <hip/hip_bf16.h>

#define NFEAT 128
#define GEMM_ROWS 8

// ---------------------------------------------------------------------------
// degree: deg[dst[e]] += 1.0f   (exact: integer-valued fp32 sums, order-free)
// ---------------------------------------------------------------------------
__global__ void deg_kernel(const int* __restrict__ dst, float* __restrict__ deg,
                           int n_edges) {
    int e = blockIdx.x * blockDim.x + threadIdx.x;
    if (e < n_edges) {
        atomicAdd(&deg[dst[e]], 1.0f);
    }
}

// ---------------------------------------------------------------------------
// scatter: agg[dst[e]][:] += X[src[e]][:]
// 32 threads per edge; each thread handles one float4 (coalesced 512B row).
// ---------------------------------------------------------------------------
__global__ void scatter_kernel(const float* __restrict__ X,
                               const int* __restrict__ src,
                               const int* __restrict__ dst,
                               float* __restrict__ agg, int n_edges) {
    int t = blockIdx.x * blockDim.x + threadIdx.x;
    int e = t >> 5;       // 32 threads per edge
    int lane = t & 31;
    if (e >= n_edges) return;
    int s = src[e];
    int d = dst[e];
    const float4 v =
        reinterpret_cast<const float4*>(X + (size_t)s * NFEAT)[lane];
    float* ap = agg + (size_t)d * NFEAT + lane * 4;
    atomicAdd(ap + 0, v.x);
    atomicAdd(ap + 1, v.y);
    atomicAdd(ap + 2, v.z);
    atomicAdd(ap + 3, v.w);
}

// ---------------------------------------------------------------------------
// fused SAGE layer GEMM: out = [relu]( X @ Ws + (agg/deg) @ Wn + b )
// Block: 256 threads, GEMM_ROWS rows of output, all 128 cols.
// Thread (g, j): g = tid>>7 in {0,1} owns rows g*4..g*4+3, col j = tid&127.
// X/out may alias (layer 2 in-place on d_out): each block reads its rows to
// LDS before writing the same rows; no cross-block row sharing.
// ---------------------------------------------------------------------------
__global__ __launch_bounds__(256) void sage_gemm_kernel(
    const float* X,                  // [N,128] (may alias out)
    const float* __restrict__ agg,   // [N,128]
    const float* __restrict__ deg,   // [N]
    const float* __restrict__ Ws,    // [128,128] row-major (fin,fout)
    const float* __restrict__ Wn,    // [128,128]
    const float* __restrict__ bias,  // [128]
    float* out,                      // [N,128]
    int n_nodes, int do_relu) {
    __shared__ float sX[GEMM_ROWS][NFEAT];
    __shared__ float sM[GEMM_ROWS][NFEAT];
    __shared__ float sWs[16][NFEAT];
    __shared__ float sWn[16][NFEAT];

    const int tid = threadIdx.x;
    const int row0 = blockIdx.x * GEMM_ROWS;

    // stage X rows and mean-neighbor rows
    for (int i = tid; i < GEMM_ROWS * NFEAT; i += 256) {
        int r = i >> 7;
        int c = i & (NFEAT - 1);
        int gr = row0 + r;
        float x = 0.f, m = 0.f;
        if (gr < n_nodes) {
            x = X[(size_t)gr * NFEAT + c];
            float dg = deg[gr];
            m = agg[(size_t)gr * NFEAT + c] / fmaxf(dg, 1.0f);
        }
        sX[r][c] = x;
        sM[r][c] = m;
    }

    const int j = tid & (NFEAT - 1);
    const int g = tid >> 7;  // row group: rows g*4 .. g*4+3
    float acc[4] = {0.f, 0.f, 0.f, 0.f};

    for (int k0 = 0; k0 < NFEAT; k0 += 16) {
        __syncthreads();  // sX/sM ready (1st iter); prev compute done (later)
        for (int i = tid; i < 16 * NFEAT; i += 256) {
            int kk = i >> 7;
            int c = i & (NFEAT - 1);
            sWs[kk][c] = Ws[(size_t)(k0 + kk) * NFEAT + c];
            sWn[kk][c] = Wn[(size_t)(k0 + kk) * NFEAT + c];
        }
        __syncthreads();
#pragma unroll
        for (int kk = 0; kk < 16; ++kk) {
            float ws = sWs[kk][j];
            float wn = sWn[kk][j];
#pragma unroll
            for (int r = 0; r < 4; ++r) {
                acc[r] += sX[g * 4 + r][k0 + kk] * ws +
                          sM[g * 4 + r][k0 + kk] * wn;
            }
        }
    }

    float bj = bias[j];
#pragma unroll
    for (int r = 0; r < 4; ++r) {
        int gr = row0 + g * 4 + r;
        if (gr < n_nodes) {
            float v = acc[r] + bj;
            if (do_relu) v = fmaxf(v, 0.f);
            out[(size_t)gr * NFEAT + j] = v;
        }
    }
}

extern "C" void kernel_launch(void* const* d_in, const int* in_sizes, int n_in,
                              void* d_out, int out_size, void* d_ws,
                              size_t ws_size, hipStream_t stream) {
    const float* h = (const float*)d_in[0];
    const int* src = (const int*)d_in[1];
    const int* dst = (const int*)d_in[2];
    const float* Ws0 = (const float*)d_in[3];
    const float* Wn0 = (const float*)d_in[4];
    const float* b0 = (const float*)d_in[5];
    const float* Ws1 = (const float*)d_in[6];
    const float* Wn1 = (const float*)d_in[7];
    const float* b1 = (const float*)d_in[8];
    float* out = (float*)d_out;

    const int n_nodes = in_sizes[0] / NFEAT;
    const int n_edges = in_sizes[1];

    float* agg = (float*)d_ws;                       // [n_nodes,128]
    float* deg = agg + (size_t)n_nodes * NFEAT;      // [n_nodes]
    const size_t agg_bytes = (size_t)n_nodes * NFEAT * sizeof(float);
    const size_t deg_bytes = (size_t)n_nodes * sizeof(float);

    const int scat_blocks = (n_edges * 32 + 255) / 256;
    const int gemm_blocks = (n_nodes + GEMM_ROWS - 1) / GEMM_ROWS;

    // ---- layer 0 ----
    hipMemsetAsync(agg, 0, agg_bytes + deg_bytes, stream);
    deg_kernel<<<(n_edges + 255) / 256, 256, 0, stream>>>(dst, deg, n_edges);
    scatter_kernel<<<scat_blocks, 256, 0, stream>>>(h, src, dst, agg, n_edges);
    sage_gemm_kernel<<<gemm_blocks, 256, 0, stream>>>(
        h, agg, deg, Ws0, Wn0, b0, out, n_nodes, 1);

    // ---- layer 1 (h1 lives in d_out; gemm reads/writes block-locally) ----
    hipMemsetAsync(agg, 0, agg_bytes, stream);
    scatter_kernel<<<scat_blocks, 256, 0, stream>>>(out, src, dst, agg,
                                                    n_edges);
    sage_gemm_kernel<<<gemm_blocks, 256, 0, stream>>>(
        out, agg, deg, Ws1, Wn1, b1, out, n_nodes, 0);
}

// Round 2
// 600.870 us; speedup vs baseline: 4.0566x; 4.0566x over previous
//
#include <hip/hip_runtime.h>
#include <hip/hip_bf16.h>

#define NFEAT 128
#define GEMM_ROWS 8

// ---------------------------------------------------------------------------
// histogram: cnt[dst[e]] += 1  (int atomics, 600K ops on 50K counters)
// ---------------------------------------------------------------------------
__global__ void hist_kernel(const int* __restrict__ dst, int* __restrict__ cnt,
                            int n_edges) {
    int e = blockIdx.x * blockDim.x + threadIdx.x;
    if (e < n_edges) atomicAdd(&cnt[dst[e]], 1);
}

// ---------------------------------------------------------------------------
// single-block exclusive scan over n counters -> row_start[0..n]
// 1024 threads, each owns a contiguous chunk; LDS Hillis-Steele over totals.
// ---------------------------------------------------------------------------
__global__ __launch_bounds__(1024) void scan_kernel(
    const int* __restrict__ cnt, int* __restrict__ row_start, int n) {
    __shared__ int ssum[1024];
    const int tid = threadIdx.x;
    const int chunk = (n + 1023) / 1024;
    const int begin = min(tid * chunk, n);
    const int end = min(begin + chunk, n);
    int s = 0;
    for (int i = begin; i < end; ++i) s += cnt[i];
    ssum[tid] = s;
    __syncthreads();
    for (int off = 1; off < 1024; off <<= 1) {
        int v = (tid >= off) ? ssum[tid - off] : 0;
        __syncthreads();
        ssum[tid] += v;
        __syncthreads();
    }
    int base = (tid > 0) ? ssum[tid - 1] : 0;
    for (int i = begin; i < end; ++i) {
        row_start[i] = base;
        base += cnt[i];
    }
    if (tid == 1023) row_start[n] = ssum[1023];
}

// ---------------------------------------------------------------------------
// fill CSR adjacency: edge_src[row_start[d] + cursor[d]++] = src[e]
// ---------------------------------------------------------------------------
__global__ void fill_kernel(const int* __restrict__ src,
                            const int* __restrict__ dst,
                            const int* __restrict__ row_start,
                            int* __restrict__ cursor,
                            int* __restrict__ edge_src, int n_edges) {
    int e = blockIdx.x * blockDim.x + threadIdx.x;
    if (e < n_edges) {
        int d = dst[e];
        int pos = row_start[d] + atomicAdd(&cursor[d], 1);
        edge_src[pos] = src[e];
    }
}

// ---------------------------------------------------------------------------
// gather-reduce mean aggregation: one wave64 per node, 2 cols/lane in regs.
// Neighbor rows are coalesced 512B reads (L2/L3-resident). No atomics.
// ---------------------------------------------------------------------------
__global__ __launch_bounds__(256) void aggregate_kernel(
    const float* __restrict__ X, const int* __restrict__ row_start,
    const int* __restrict__ edge_src, float* __restrict__ M, int n_nodes) {
    const int wave = (blockIdx.x * blockDim.x + threadIdx.x) >> 6;
    const int lane = threadIdx.x & 63;
    if (wave >= n_nodes) return;
    const int beg = row_start[wave];
    const int end = row_start[wave + 1];
    float ax = 0.f, ay = 0.f, bx = 0.f, by = 0.f;
    int i = beg;
    for (; i + 1 < end; i += 2) {  // 2 independent loads/iter for latency ILP
        int s0 = edge_src[i];
        int s1 = edge_src[i + 1];
        float2 v0 = reinterpret_cast<const float2*>(X + (size_t)s0 * NFEAT)[lane];
        float2 v1 = reinterpret_cast<const float2*>(X + (size_t)s1 * NFEAT)[lane];
        ax += v0.x; ay += v0.y;
        bx += v1.x; by += v1.y;
    }
    if (i < end) {
        int s0 = edge_src[i];
        float2 v0 = reinterpret_cast<const float2*>(X + (size_t)s0 * NFEAT)[lane];
        ax += v0.x; ay += v0.y;
    }
    const float inv = 1.0f / fmaxf((float)(end - beg), 1.0f);
    float2 r;
    r.x = (ax + bx) * inv;
    r.y = (ay + by) * inv;
    reinterpret_cast<float2*>(M + (size_t)wave * NFEAT)[lane] = r;
}

// ---------------------------------------------------------------------------
// fused SAGE layer GEMM: out = [relu]( X @ Ws + M @ Wn + b )
// X/out may alias: each block reads only its OWN rows of X (to LDS) before
// writing those same rows; M is a separate buffer.
// ---------------------------------------------------------------------------
__global__ __launch_bounds__(256) void sage_gemm_kernel(
    const float* X,                  // [N,128] (may alias out)
    const float* __restrict__ M,     // [N,128] mean-neighbor rows
    const float* __restrict__ Ws,    // [128,128] (fin,fout)
    const float* __restrict__ Wn,    // [128,128]
    const float* __restrict__ bias,  // [128]
    float* out,                      // [N,128]
    int n_nodes, int do_relu) {
    __shared__ float sX[GEMM_ROWS][NFEAT];
    __shared__ float sM[GEMM_ROWS][NFEAT];
    __shared__ float sWs[16][NFEAT];
    __shared__ float sWn[16][NFEAT];

    const int tid = threadIdx.x;
    const int row0 = blockIdx.x * GEMM_ROWS;

    for (int i = tid; i < GEMM_ROWS * NFEAT; i += 256) {
        int r = i >> 7;
        int c = i & (NFEAT - 1);
        int gr = row0 + r;
        float x = 0.f, m = 0.f;
        if (gr < n_nodes) {
            x = X[(size_t)gr * NFEAT + c];
            m = M[(size_t)gr * NFEAT + c];
        }
        sX[r][c] = x;
        sM[r][c] = m;
    }

    const int j = tid & (NFEAT - 1);
    const int g = tid >> 7;
    float acc[4] = {0.f, 0.f, 0.f, 0.f};

    for (int k0 = 0; k0 < NFEAT; k0 += 16) {
        __syncthreads();
        for (int i = tid; i < 16 * NFEAT; i += 256) {
            int kk = i >> 7;
            int c = i & (NFEAT - 1);
            sWs[kk][c] = Ws[(size_t)(k0 + kk) * NFEAT + c];
            sWn[kk][c] = Wn[(size_t)(k0 + kk) * NFEAT + c];
        }
        __syncthreads();
#pragma unroll
        for (int kk = 0; kk < 16; ++kk) {
            float ws = sWs[kk][j];
            float wn = sWn[kk][j];
#pragma unroll
            for (int r = 0; r < 4; ++r) {
                acc[r] += sX[g * 4 + r][k0 + kk] * ws +
                          sM[g * 4 + r][k0 + kk] * wn;
            }
        }
    }

    float bj = bias[j];
#pragma unroll
    for (int r = 0; r < 4; ++r) {
        int gr = row0 + g * 4 + r;
        if (gr < n_nodes) {
            float v = acc[r] + bj;
            if (do_relu) v = fmaxf(v, 0.f);
            out[(size_t)gr * NFEAT + j] = v;
        }
    }
}

extern "C" void kernel_launch(void* const* d_in, const int* in_sizes, int n_in,
                              void* d_out, int out_size, void* d_ws,
                              size_t ws_size, hipStream_t stream) {
    const float* h = (const float*)d_in[0];
    const int* src = (const int*)d_in[1];
    const int* dst = (const int*)d_in[2];
    const float* Ws0 = (const float*)d_in[3];
    const float* Wn0 = (const float*)d_in[4];
    const float* b0 = (const float*)d_in[5];
    const float* Ws1 = (const float*)d_in[6];
    const float* Wn1 = (const float*)d_in[7];
    const float* b1 = (const float*)d_in[8];
    float* out = (float*)d_out;

    const int n_nodes = in_sizes[0] / NFEAT;
    const int n_edges = in_sizes[1];

    // workspace layout
    float* Mbuf = (float*)d_ws;                              // [N,128]
    int* row_start = (int*)(Mbuf + (size_t)n_nodes * NFEAT); // [N+1]
    int* cnt = row_start + (n_nodes + 1);                    // [N]
    int* cursor = cnt + n_nodes;                             // [N]
    int* edge_src = cursor + n_nodes;                        // [E]

    // ---- CSR build (shared by both layers) ----
    hipMemsetAsync(cnt, 0, (size_t)n_nodes * sizeof(int), stream);
    hipMemsetAsync(cursor, 0, (size_t)n_nodes * sizeof(int), stream);
    hist_kernel<<<(n_edges + 255) / 256, 256, 0, stream>>>(dst, cnt, n_edges);
    scan_kernel<<<1, 1024, 0, stream>>>(cnt, row_start, n_nodes);
    fill_kernel<<<(n_edges + 255) / 256, 256, 0, stream>>>(
        src, dst, row_start, cursor, edge_src, n_edges);

    const int agg_blocks = (n_nodes * 64 + 255) / 256;  // one wave per node
    const int gemm_blocks = (n_nodes + GEMM_ROWS - 1) / GEMM_ROWS;

    // ---- layer 0 ----
    aggregate_kernel<<<agg_blocks, 256, 0, stream>>>(h, row_start, edge_src,
                                                     Mbuf, n_nodes);
    sage_gemm_kernel<<<gemm_blocks, 256, 0, stream>>>(h, Mbuf, Ws0, Wn0, b0,
                                                      out, n_nodes, 1);

    // ---- layer 1 (h1 in d_out; aggregate fully reads it before GEMM
    //      overwrites; GEMM reads only its own rows of d_out) ----
    aggregate_kernel<<<agg_blocks, 256, 0, stream>>>(out, row_start, edge_src,
                                                     Mbuf, n_nodes);
    sage_gemm_kernel<<<gemm_blocks, 256, 0, stream>>>(out, Mbuf, Ws1, Wn1, b1,
                                                      out, n_nodes, 0);
}

// Round 3
// 316.471 us; speedup vs baseline: 7.7021x; 1.8987x over previous
//
#include <hip/hip_runtime.h>
#include <hip/hip_bf16.h>

#define NFEAT 128

typedef __attribute__((ext_vector_type(8))) short bf16x8;
typedef __attribute__((ext_vector_type(4))) float f32x4;

__device__ inline unsigned short f2bf(float f) {  // RNE f32 -> bf16
    unsigned int u = __float_as_uint(f);
    u += 0x7fffu + ((u >> 16) & 1u);
    return (unsigned short)(u >> 16);
}
__device__ inline unsigned int pack2bf(float lo, float hi) {
    return (unsigned int)f2bf(lo) | ((unsigned int)f2bf(hi) << 16);
}

// ---------------------------------------------------------------------------
// convert f32 -> bf16, 4 elems/thread
// ---------------------------------------------------------------------------
__global__ void convert_kernel(const float* __restrict__ in,
                               unsigned short* __restrict__ out, int n4) {
    int i = blockIdx.x * blockDim.x + threadIdx.x;
    if (i >= n4) return;
    float4 v = reinterpret_cast<const float4*>(in)[i];
    uint2 o;
    o.x = pack2bf(v.x, v.y);
    o.y = pack2bf(v.z, v.w);
    reinterpret_cast<uint2*>(out)[i] = o;
}

// ---------------------------------------------------------------------------
// weights: WcT[layer][j][k] bf16, k<128 -> Ws[k][j], k>=128 -> Wn[k-128][j]
// ---------------------------------------------------------------------------
__global__ void prep_weights_kernel(const float* __restrict__ Ws0,
                                    const float* __restrict__ Wn0,
                                    const float* __restrict__ Ws1,
                                    const float* __restrict__ Wn1,
                                    unsigned short* __restrict__ WcT) {
    int idx = blockIdx.x * blockDim.x + threadIdx.x;
    if (idx >= 2 * 128 * 256) return;
    int layer = idx >> 15;
    int rem = idx & 32767;
    int j = rem >> 8;
    int k = rem & 255;
    const float* Ws = layer ? Ws1 : Ws0;
    const float* Wn = layer ? Wn1 : Wn0;
    float v = (k < 128) ? Ws[k * 128 + j] : Wn[(k - 128) * 128 + j];
    WcT[idx & ~32767 ? (32768 + j * 256 + k) : (j * 256 + k)] = f2bf(v);
}

// ---------------------------------------------------------------------------
// CSR build: histogram -> scan -> fill (cnt doubles as fill cursor)
// ---------------------------------------------------------------------------
__global__ void hist_kernel(const int* __restrict__ dst, int* __restrict__ cnt,
                            int n_edges) {
    int e = blockIdx.x * blockDim.x + threadIdx.x;
    if (e < n_edges) atomicAdd(&cnt[dst[e]], 1);
}

__global__ __launch_bounds__(1024) void scan_kernel(
    const int* __restrict__ cnt, int* __restrict__ row_start, int n) {
    __shared__ int ssum[1024];
    const int tid = threadIdx.x;
    const int chunk = (n + 1023) / 1024;
    const int begin = min(tid * chunk, n);
    const int end = min(begin + chunk, n);
    int s = 0;
    for (int i = begin; i < end; ++i) s += cnt[i];
    ssum[tid] = s;
    __syncthreads();
    for (int off = 1; off < 1024; off <<= 1) {
        int v = (tid >= off) ? ssum[tid - off] : 0;
        __syncthreads();
        ssum[tid] += v;
        __syncthreads();
    }
    int base = (tid > 0) ? ssum[tid - 1] : 0;
    for (int i = begin; i < end; ++i) {
        row_start[i] = base;
        base += cnt[i];
    }
    if (tid == 1023) row_start[n] = ssum[1023];
}

__global__ void fill_kernel(const int* __restrict__ src,
                            const int* __restrict__ dst,
                            const int* __restrict__ row_start,
                            int* __restrict__ cnt,  // consumed as cursor
                            int* __restrict__ edge_src, int n_edges) {
    int e = blockIdx.x * blockDim.x + threadIdx.x;
    if (e < n_edges) {
        int d = dst[e];
        int pos = row_start[d] + atomicSub(&cnt[d], 1) - 1;
        edge_src[pos] = src[e];
    }
}

// ---------------------------------------------------------------------------
// mean aggregation over bf16 rows: one wave per node, 2 cols/lane (4B/lane,
// 256B coalesced per row), f32 accumulate, bf16 out. No atomics.
// ---------------------------------------------------------------------------
__global__ __launch_bounds__(256) void aggregate_kernel(
    const unsigned short* __restrict__ Xbf, const int* __restrict__ row_start,
    const int* __restrict__ edge_src, unsigned short* __restrict__ Mbf,
    int n_nodes) {
    const int wave = (blockIdx.x * blockDim.x + threadIdx.x) >> 6;
    const int lane = threadIdx.x & 63;
    if (wave >= n_nodes) return;
    const int beg = row_start[wave];
    const int end = row_start[wave + 1];
    float a0 = 0.f, a1 = 0.f, b0 = 0.f, b1 = 0.f;
    int i = beg;
    for (; i + 1 < end; i += 2) {
        int s0 = edge_src[i];
        int s1 = edge_src[i + 1];
        unsigned int v0 =
            reinterpret_cast<const unsigned int*>(Xbf + (size_t)s0 * NFEAT)[lane];
        unsigned int v1 =
            reinterpret_cast<const unsigned int*>(Xbf + (size_t)s1 * NFEAT)[lane];
        a0 += __uint_as_float((v0 & 0xffffu) << 16);
        a1 += __uint_as_float(v0 & 0xffff0000u);
        b0 += __uint_as_float((v1 & 0xffffu) << 16);
        b1 += __uint_as_float(v1 & 0xffff0000u);
    }
    if (i < end) {
        int s0 = edge_src[i];
        unsigned int v0 =
            reinterpret_cast<const unsigned int*>(Xbf + (size_t)s0 * NFEAT)[lane];
        a0 += __uint_as_float((v0 & 0xffffu) << 16);
        a1 += __uint_as_float(v0 & 0xffff0000u);
    }
    const float inv = 1.0f / fmaxf((float)(end - beg), 1.0f);
    reinterpret_cast<unsigned int*>(Mbf + (size_t)wave * NFEAT)[lane] =
        pack2bf((a0 + b0) * inv, (a1 + b1) * inv);
}

// ---------------------------------------------------------------------------
// MFMA GEMM: out = [relu]( [Xbf | Mbf] @ WcT^T + b ),  K=256, 16x16x32 bf16.
// Block: 256 thr = 4 waves; each wave owns 16 rows x 128 cols (8 N-tiles).
// A-frags and B-frags loaded straight from global (L2-resident), no LDS.
// In-place out_bf==Xbf is safe: each wave writes only rows it alone read.
// ---------------------------------------------------------------------------
__global__ __launch_bounds__(256) void mfma_gemm_kernel(
    const unsigned short* __restrict__ Xbf,  // [N,128] bf16
    const unsigned short* __restrict__ Mbf,  // [N,128] bf16
    const unsigned short* __restrict__ WcT,  // [128][256] bf16 (j-major)
    const float* __restrict__ bias,          // [128] f32
    unsigned short* out_bf,                  // bf16 out (or null)
    float* out_f32,                          // f32 out (or null)
    int n_nodes, int do_relu) {
    const int tid = threadIdx.x;
    const int wave = tid >> 6;
    const int lane = tid & 63;
    const int row_base = blockIdx.x * 64 + wave * 16;
    const int l15 = lane & 15;
    const int kgrp = (lane >> 4) * 8;  // 0,8,16,24

    const int arow = min(row_base + l15, n_nodes - 1);
    const unsigned short* Arow = Xbf + (size_t)arow * NFEAT;
    const unsigned short* Mrow = Mbf + (size_t)arow * NFEAT;

    f32x4 acc[8];
#pragma unroll
    for (int t = 0; t < 8; ++t) acc[t] = (f32x4){0.f, 0.f, 0.f, 0.f};

#pragma unroll
    for (int k0 = 0; k0 < 256; k0 += 32) {
        bf16x8 a;
        if (k0 < 128)
            a = *reinterpret_cast<const bf16x8*>(Arow + k0 + kgrp);
        else
            a = *reinterpret_cast<const bf16x8*>(Mrow + (k0 - 128) + kgrp);
#pragma unroll
        for (int t = 0; t < 8; ++t) {
            bf16x8 b = *reinterpret_cast<const bf16x8*>(
                WcT + (size_t)(t * 16 + l15) * 256 + k0 + kgrp);
            acc[t] = __builtin_amdgcn_mfma_f32_16x16x32_bf16(a, b, acc[t], 0, 0, 0);
        }
    }

    // C/D layout: col = lane&15, row = (lane>>4)*4 + reg
    const int crow0 = row_base + (lane >> 4) * 4;
#pragma unroll
    for (int t = 0; t < 8; ++t) {
        const int c = t * 16 + l15;
        const float bj = bias[c];
#pragma unroll
        for (int r = 0; r < 4; ++r) {
            const int gr = crow0 + r;
            if (gr < n_nodes) {
                float v = acc[t][r] + bj;
                if (do_relu) v = fmaxf(v, 0.f);
                if (out_f32)
                    out_f32[(size_t)gr * NFEAT + c] = v;
                else
                    out_bf[(size_t)gr * NFEAT + c] = f2bf(v);
            }
        }
    }
}

extern "C" void kernel_launch(void* const* d_in, const int* in_sizes, int n_in,
                              void* d_out, int out_size, void* d_ws,
                              size_t ws_size, hipStream_t stream) {
    const float* h = (const float*)d_in[0];
    const int* src = (const int*)d_in[1];
    const int* dst = (const int*)d_in[2];
    const float* Ws0 = (const float*)d_in[3];
    const float* Wn0 = (const float*)d_in[4];
    const float* b0 = (const float*)d_in[5];
    const float* Ws1 = (const float*)d_in[6];
    const float* Wn1 = (const float*)d_in[7];
    const float* b1 = (const float*)d_in[8];
    float* out = (float*)d_out;

    const int n_nodes = in_sizes[0] / NFEAT;
    const int n_edges = in_sizes[1];

    // workspace layout (~28.5 MB)
    unsigned short* hbf = (unsigned short*)d_ws;        // [N,128] bf16 (also h1)
    unsigned short* Mbf = hbf + (size_t)n_nodes * NFEAT;  // [N,128] bf16
    unsigned short* WcT = Mbf + (size_t)n_nodes * NFEAT;  // 2*[128][256] bf16
    int* row_start = (int*)(WcT + 2 * 128 * 256);       // [N+1]
    int* cnt = row_start + (n_nodes + 1);               // [N]
    int* edge_src = cnt + n_nodes;                      // [E]

    // prep: weights + bf16 activations + CSR
    hipMemsetAsync(cnt, 0, (size_t)n_nodes * sizeof(int), stream);
    prep_weights_kernel<<<(2 * 128 * 256 + 255) / 256, 256, 0, stream>>>(
        Ws0, Wn0, Ws1, Wn1, WcT);
    convert_kernel<<<(n_nodes * NFEAT / 4 + 255) / 256, 256, 0, stream>>>(
        h, hbf, n_nodes * NFEAT / 4);
    hist_kernel<<<(n_edges + 255) / 256, 256, 0, stream>>>(dst, cnt, n_edges);
    scan_kernel<<<1, 1024, 0, stream>>>(cnt, row_start, n_nodes);
    fill_kernel<<<(n_edges + 255) / 256, 256, 0, stream>>>(
        src, dst, row_start, cnt, edge_src, n_edges);

    const int agg_blocks = (n_nodes * 64 + 255) / 256;
    const int gemm_blocks = (n_nodes + 63) / 64;

    // ---- layer 0 (h1 bf16 written in-place over hbf) ----
    aggregate_kernel<<<agg_blocks, 256, 0, stream>>>(hbf, row_start, edge_src,
                                                     Mbf, n_nodes);
    mfma_gemm_kernel<<<gemm_blocks, 256, 0, stream>>>(
        hbf, Mbf, WcT, b0, hbf, (float*)nullptr, n_nodes, 1);

    // ---- layer 1 (f32 out to d_out) ----
    aggregate_kernel<<<agg_blocks, 256, 0, stream>>>(hbf, row_start, edge_src,
                                                     Mbf, n_nodes);
    mfma_gemm_kernel<<<gemm_blocks, 256, 0, stream>>>(
        hbf, Mbf, WcT + 32768, b1, (unsigned short*)nullptr, out, n_nodes, 0);
}

// Round 4
// 231.209 us; speedup vs baseline: 10.5424x; 1.3688x over previous
//
#include <hip/hip_runtime.h>
#include <hip/hip_bf16.h>

#define NFEAT 128

typedef __attribute__((ext_vector_type(8))) short bf16x8;
typedef __attribute__((ext_vector_type(4))) float f32x4;

__device__ inline unsigned short f2bf(float f) {  // RNE f32 -> bf16
    unsigned int u = __float_as_uint(f);
    u += 0x7fffu + ((u >> 16) & 1u);
    return (unsigned short)(u >> 16);
}
__device__ inline unsigned int pack2bf(float lo, float hi) {
    return (unsigned int)f2bf(lo) | ((unsigned int)f2bf(hi) << 16);
}
__device__ inline float bflo(unsigned int v) {
    return __uint_as_float((v & 0xffffu) << 16);
}
__device__ inline float bfhi(unsigned int v) {
    return __uint_as_float(v & 0xffff0000u);
}

// ---------------------------------------------------------------------------
// convert f32 -> bf16, 4 elems/thread
// ---------------------------------------------------------------------------
__global__ void convert_kernel(const float* __restrict__ in,
                               unsigned short* __restrict__ out, int n4) {
    int i = blockIdx.x * blockDim.x + threadIdx.x;
    if (i >= n4) return;
    float4 v = reinterpret_cast<const float4*>(in)[i];
    uint2 o;
    o.x = pack2bf(v.x, v.y);
    o.y = pack2bf(v.z, v.w);
    reinterpret_cast<uint2*>(out)[i] = o;
}

// ---------------------------------------------------------------------------
// weights: WcT[layer][j][k] bf16, k<128 -> Ws[k][j], k>=128 -> Wn[k-128][j]
// ---------------------------------------------------------------------------
__global__ void prep_weights_kernel(const float* __restrict__ Ws0,
                                    const float* __restrict__ Wn0,
                                    const float* __restrict__ Ws1,
                                    const float* __restrict__ Wn1,
                                    unsigned short* __restrict__ WcT) {
    int idx = blockIdx.x * blockDim.x + threadIdx.x;
    if (idx >= 2 * 128 * 256) return;
    int layer = idx >> 15;
    int rem = idx & 32767;
    int j = rem >> 8;
    int k = rem & 255;
    const float* Ws = layer ? Ws1 : Ws0;
    const float* Wn = layer ? Wn1 : Wn0;
    float v = (k < 128) ? Ws[k * 128 + j] : Wn[(k - 128) * 128 + j];
    WcT[layer * 32768 + j * 256 + k] = f2bf(v);
}

// ---------------------------------------------------------------------------
// CSR build: histogram -> hierarchical scan (A,B,C) -> fill
// ---------------------------------------------------------------------------
__global__ void hist_kernel(const int* __restrict__ dst, int* __restrict__ cnt,
                            int n_edges) {
    int e = blockIdx.x * blockDim.x + threadIdx.x;
    if (e < n_edges) atomicAdd(&cnt[dst[e]], 1);
}

// A: per-block (256-elem) sums, coalesced
__global__ __launch_bounds__(256) void scan_blocksum_kernel(
    const int* __restrict__ cnt, int* __restrict__ blocksum, int n) {
    __shared__ int s[256];
    int i = blockIdx.x * 256 + threadIdx.x;
    s[threadIdx.x] = (i < n) ? cnt[i] : 0;
    __syncthreads();
    for (int off = 128; off > 0; off >>= 1) {
        if (threadIdx.x < off) s[threadIdx.x] += s[threadIdx.x + off];
        __syncthreads();
    }
    if (threadIdx.x == 0) blocksum[blockIdx.x] = s[0];
}

// B: single block scans block sums (nblk <= 1024), writes row_start[n]=total
__global__ __launch_bounds__(1024) void scan_blockoff_kernel(
    const int* __restrict__ blocksum, int* __restrict__ blockoff,
    int* __restrict__ row_start, int nblk, int n) {
    __shared__ int s[1024];
    const int tid = threadIdx.x;
    int v = (tid < nblk) ? blocksum[tid] : 0;
    s[tid] = v;
    __syncthreads();
    for (int off = 1; off < 1024; off <<= 1) {
        int t = (tid >= off) ? s[tid - off] : 0;
        __syncthreads();
        s[tid] += t;
        __syncthreads();
    }
    if (tid < nblk) blockoff[tid] = s[tid] - v;  // exclusive
    if (tid == 1023) row_start[n] = s[1023];
}

// C: per-block exclusive scan + block offset, coalesced read/write
__global__ __launch_bounds__(256) void scan_final_kernel(
    const int* __restrict__ cnt, const int* __restrict__ blockoff,
    int* __restrict__ row_start, int n) {
    __shared__ int s[256];
    const int tid = threadIdx.x;
    int i = blockIdx.x * 256 + tid;
    int v = (i < n) ? cnt[i] : 0;
    s[tid] = v;
    __syncthreads();
    for (int off = 1; off < 256; off <<= 1) {
        int t = (tid >= off) ? s[tid - off] : 0;
        __syncthreads();
        s[tid] += t;
        __syncthreads();
    }
    if (i < n) row_start[i] = blockoff[blockIdx.x] + s[tid] - v;
}

__global__ void fill_kernel(const int* __restrict__ src,
                            const int* __restrict__ dst,
                            const int* __restrict__ row_start,
                            int* __restrict__ cnt,  // consumed as cursor
                            int* __restrict__ edge_src, int n_edges) {
    int e = blockIdx.x * blockDim.x + threadIdx.x;
    if (e < n_edges) {
        int d = dst[e];
        int pos = row_start[d] + atomicSub(&cnt[d], 1) - 1;
        edge_src[pos] = src[e];
    }
}

// ---------------------------------------------------------------------------
// mean aggregation over bf16 rows: one wave per node, 2 cols/lane (4B/lane,
// 256B coalesced per row), f32 accumulate, bf16 out, 4-deep load ILP.
// ---------------------------------------------------------------------------
__global__ __launch_bounds__(256) void aggregate_kernel(
    const unsigned short* __restrict__ Xbf, const int* __restrict__ row_start,
    const int* __restrict__ edge_src, unsigned short* __restrict__ Mbf,
    int n_nodes) {
    const int wave = (blockIdx.x * blockDim.x + threadIdx.x) >> 6;
    const int lane = threadIdx.x & 63;
    if (wave >= n_nodes) return;
    const int beg = row_start[wave];
    const int end = row_start[wave + 1];
    float a0 = 0.f, a1 = 0.f, b0 = 0.f, b1 = 0.f;
    float c0 = 0.f, c1 = 0.f, d0 = 0.f, d1 = 0.f;
    int i = beg;
    for (; i + 3 < end; i += 4) {
        int s0 = edge_src[i];
        int s1 = edge_src[i + 1];
        int s2 = edge_src[i + 2];
        int s3 = edge_src[i + 3];
        unsigned int v0 =
            reinterpret_cast<const unsigned int*>(Xbf + (size_t)s0 * NFEAT)[lane];
        unsigned int v1 =
            reinterpret_cast<const unsigned int*>(Xbf + (size_t)s1 * NFEAT)[lane];
        unsigned int v2 =
            reinterpret_cast<const unsigned int*>(Xbf + (size_t)s2 * NFEAT)[lane];
        unsigned int v3 =
            reinterpret_cast<const unsigned int*>(Xbf + (size_t)s3 * NFEAT)[lane];
        a0 += bflo(v0); a1 += bfhi(v0);
        b0 += bflo(v1); b1 += bfhi(v1);
        c0 += bflo(v2); c1 += bfhi(v2);
        d0 += bflo(v3); d1 += bfhi(v3);
    }
    for (; i < end; ++i) {
        int s0 = edge_src[i];
        unsigned int v0 =
            reinterpret_cast<const unsigned int*>(Xbf + (size_t)s0 * NFEAT)[lane];
        a0 += bflo(v0); a1 += bfhi(v0);
    }
    const float inv = 1.0f / fmaxf((float)(end - beg), 1.0f);
    reinterpret_cast<unsigned int*>(Mbf + (size_t)wave * NFEAT)[lane] =
        pack2bf((a0 + b0 + c0 + d0) * inv, (a1 + b1 + c1 + d1) * inv);
}

// ---------------------------------------------------------------------------
// MFMA GEMM: out = [relu]( [Xbf | Mbf] @ WcT^T + b ),  K=256, 16x16x32 bf16.
// Block: 256 thr = 4 waves; each wave owns 16 rows x 128 cols (8 N-tiles).
// A/B fragments loaded straight from global (L2-resident), no LDS.
// In-place out_bf==Xbf is safe: each wave writes only rows it alone read.
// ---------------------------------------------------------------------------
__global__ __launch_bounds__(256) void mfma_gemm_kernel(
    const unsigned short* __restrict__ Xbf,  // [N,128] bf16
    const unsigned short* __restrict__ Mbf,  // [N,128] bf16
    const unsigned short* __restrict__ WcT,  // [128][256] bf16 (j-major)
    const float* __restrict__ bias,          // [128] f32
    unsigned short* out_bf,                  // bf16 out (or null)
    float* out_f32,                          // f32 out (or null)
    int n_nodes, int do_relu) {
    const int tid = threadIdx.x;
    const int wave = tid >> 6;
    const int lane = tid & 63;
    const int row_base = blockIdx.x * 64 + wave * 16;
    const int l15 = lane & 15;
    const int kgrp = (lane >> 4) * 8;  // 0,8,16,24

    const int arow = min(row_base + l15, n_nodes - 1);
    const unsigned short* Arow = Xbf + (size_t)arow * NFEAT;
    const unsigned short* Mrow = Mbf + (size_t)arow * NFEAT;

    f32x4 acc[8];
#pragma unroll
    for (int t = 0; t < 8; ++t) acc[t] = (f32x4){0.f, 0.f, 0.f, 0.f};

#pragma unroll
    for (int k0 = 0; k0 < 256; k0 += 32) {
        bf16x8 a;
        if (k0 < 128)
            a = *reinterpret_cast<const bf16x8*>(Arow + k0 + kgrp);
        else
            a = *reinterpret_cast<const bf16x8*>(Mrow + (k0 - 128) + kgrp);
#pragma unroll
        for (int t = 0; t < 8; ++t) {
            bf16x8 b = *reinterpret_cast<const bf16x8*>(
                WcT + (size_t)(t * 16 + l15) * 256 + k0 + kgrp);
            acc[t] = __builtin_amdgcn_mfma_f32_16x16x32_bf16(a, b, acc[t], 0, 0, 0);
        }
    }

    // C/D layout: col = lane&15, row = (lane>>4)*4 + reg
    const int crow0 = row_base + (lane >> 4) * 4;
#pragma unroll
    for (int t = 0; t < 8; ++t) {
        const int c = t * 16 + l15;
        const float bj = bias[c];
#pragma unroll
        for (int r = 0; r < 4; ++r) {
            const int gr = crow0 + r;
            if (gr < n_nodes) {
                float v = acc[t][r] + bj;
                if (do_relu) v = fmaxf(v, 0.f);
                if (out_f32)
                    out_f32[(size_t)gr * NFEAT + c] = v;
                else
                    out_bf[(size_t)gr * NFEAT + c] = f2bf(v);
            }
        }
    }
}

extern "C" void kernel_launch(void* const* d_in, const int* in_sizes, int n_in,
                              void* d_out, int out_size, void* d_ws,
                              size_t ws_size, hipStream_t stream) {
    const float* h = (const float*)d_in[0];
    const int* src = (const int*)d_in[1];
    const int* dst = (const int*)d_in[2];
    const float* Ws0 = (const float*)d_in[3];
    const float* Wn0 = (const float*)d_in[4];
    const float* b0 = (const float*)d_in[5];
    const float* Ws1 = (const float*)d_in[6];
    const float* Wn1 = (const float*)d_in[7];
    const float* b1 = (const float*)d_in[8];
    float* out = (float*)d_out;

    const int n_nodes = in_sizes[0] / NFEAT;
    const int n_edges = in_sizes[1];
    const int nblk = (n_nodes + 255) / 256;  // scan blocks (196 <= 1024)

    // workspace layout (~28.5 MB)
    unsigned short* hbf = (unsigned short*)d_ws;          // [N,128] bf16 (+h1)
    unsigned short* Mbf = hbf + (size_t)n_nodes * NFEAT;  // [N,128] bf16
    unsigned short* WcT = Mbf + (size_t)n_nodes * NFEAT;  // 2*[128][256] bf16
    int* row_start = (int*)(WcT + 2 * 128 * 256);         // [N+1]
    int* cnt = row_start + (n_nodes + 1);                 // [N]
    int* edge_src = cnt + n_nodes;                        // [E]
    // scan scratch aliases Mbf (dead until aggregate, which runs after CSR)
    int* blocksum = (int*)Mbf;       // [nblk]
    int* blockoff = blocksum + nblk; // [nblk]

    // prep: weights + bf16 activations + CSR
    hipMemsetAsync(cnt, 0, (size_t)n_nodes * sizeof(int), stream);
    prep_weights_kernel<<<(2 * 128 * 256 + 255) / 256, 256, 0, stream>>>(
        Ws0, Wn0, Ws1, Wn1, WcT);
    convert_kernel<<<(n_nodes * NFEAT / 4 + 255) / 256, 256, 0, stream>>>(
        h, hbf, n_nodes * NFEAT / 4);
    hist_kernel<<<(n_edges + 255) / 256, 256, 0, stream>>>(dst, cnt, n_edges);
    scan_blocksum_kernel<<<nblk, 256, 0, stream>>>(cnt, blocksum, n_nodes);
    scan_blockoff_kernel<<<1, 1024, 0, stream>>>(blocksum, blockoff, row_start,
                                                 nblk, n_nodes);
    scan_final_kernel<<<nblk, 256, 0, stream>>>(cnt, blockoff, row_start,
                                                n_nodes);
    fill_kernel<<<(n_edges + 255) / 256, 256, 0, stream>>>(
        src, dst, row_start, cnt, edge_src, n_edges);

    const int agg_blocks = (n_nodes * 64 + 255) / 256;
    const int gemm_blocks = (n_nodes + 63) / 64;

    // ---- layer 0 (h1 bf16 written in-place over hbf) ----
    aggregate_kernel<<<agg_blocks, 256, 0, stream>>>(hbf, row_start, edge_src,
                                                     Mbf, n_nodes);
    mfma_gemm_kernel<<<gemm_blocks, 256, 0, stream>>>(
        hbf, Mbf, WcT, b0, hbf, (float*)nullptr, n_nodes, 1);

    // ---- layer 1 (f32 out to d_out) ----
    aggregate_kernel<<<agg_blocks, 256, 0, stream>>>(hbf, row_start, edge_src,
                                                     Mbf, n_nodes);
    mfma_gemm_kernel<<<gemm_blocks, 256, 0, stream>>>(
        hbf, Mbf, WcT + 32768, b1, (unsigned short*)nullptr, out, n_nodes, 0);
}

// Round 5
// 179.956 us; speedup vs baseline: 13.5450x; 1.2848x over previous
//
#include <hip/hip_runtime.h>
#include <hip/hip_bf16.h>

#define NFEAT 128

typedef __attribute__((ext_vector_type(8))) short bf16x8;
typedef __attribute__((ext_vector_type(4))) float f32x4;

__device__ inline unsigned short f2bf(float f) {  // RNE f32 -> bf16
    unsigned int u = __float_as_uint(f);
    u += 0x7fffu + ((u >> 16) & 1u);
    return (unsigned short)(u >> 16);
}
__device__ inline unsigned int pack2bf(float lo, float hi) {
    return (unsigned int)f2bf(lo) | ((unsigned int)f2bf(hi) << 16);
}
__device__ inline float bflo(unsigned int v) {
    return __uint_as_float((v & 0xffffu) << 16);
}
__device__ inline float bfhi(unsigned int v) {
    return __uint_as_float(v & 0xffff0000u);
}

// ---------------------------------------------------------------------------
// zero int buffer (replaces pathological rocclr fillBuffer: 43.7us -> ~3us)
// ---------------------------------------------------------------------------
__global__ void zero_kernel(int* __restrict__ p, int n) {
    int i = blockIdx.x * blockDim.x + threadIdx.x;
    if (i < n) p[i] = 0;
}

// ---------------------------------------------------------------------------
// convert f32 -> bf16, 4 elems/thread
// ---------------------------------------------------------------------------
__global__ void convert_kernel(const float* __restrict__ in,
                               unsigned short* __restrict__ out, int n4) {
    int i = blockIdx.x * blockDim.x + threadIdx.x;
    if (i >= n4) return;
    float4 v = reinterpret_cast<const float4*>(in)[i];
    uint2 o;
    o.x = pack2bf(v.x, v.y);
    o.y = pack2bf(v.z, v.w);
    reinterpret_cast<uint2*>(out)[i] = o;
}

// ---------------------------------------------------------------------------
// weights: WcT[layer][j][k] bf16, k<128 -> Ws[k][j], k>=128 -> Wn[k-128][j]
// ---------------------------------------------------------------------------
__global__ void prep_weights_kernel(const float* __restrict__ Ws0,
                                    const float* __restrict__ Wn0,
                                    const float* __restrict__ Ws1,
                                    const float* __restrict__ Wn1,
                                    unsigned short* __restrict__ WcT) {
    int idx = blockIdx.x * blockDim.x + threadIdx.x;
    if (idx >= 2 * 128 * 256) return;
    int layer = idx >> 15;
    int rem = idx & 32767;
    int j = rem >> 8;
    int k = rem & 255;
    const float* Ws = layer ? Ws1 : Ws0;
    const float* Wn = layer ? Wn1 : Wn0;
    float v = (k < 128) ? Ws[k * 128 + j] : Wn[(k - 128) * 128 + j];
    WcT[layer * 32768 + j * 256 + k] = f2bf(v);
}

// ---------------------------------------------------------------------------
// CSR build: histogram -> hierarchical scan (A,B,C) -> fill
// ---------------------------------------------------------------------------
__global__ void hist_kernel(const int* __restrict__ dst, int* __restrict__ cnt,
                            int n_edges) {
    int e = blockIdx.x * blockDim.x + threadIdx.x;
    if (e < n_edges) atomicAdd(&cnt[dst[e]], 1);
}

__global__ __launch_bounds__(256) void scan_blocksum_kernel(
    const int* __restrict__ cnt, int* __restrict__ blocksum, int n) {
    __shared__ int s[256];
    int i = blockIdx.x * 256 + threadIdx.x;
    s[threadIdx.x] = (i < n) ? cnt[i] : 0;
    __syncthreads();
    for (int off = 128; off > 0; off >>= 1) {
        if (threadIdx.x < off) s[threadIdx.x] += s[threadIdx.x + off];
        __syncthreads();
    }
    if (threadIdx.x == 0) blocksum[blockIdx.x] = s[0];
}

__global__ __launch_bounds__(1024) void scan_blockoff_kernel(
    const int* __restrict__ blocksum, int* __restrict__ blockoff,
    int* __restrict__ row_start, int nblk, int n) {
    __shared__ int s[1024];
    const int tid = threadIdx.x;
    int v = (tid < nblk) ? blocksum[tid] : 0;
    s[tid] = v;
    __syncthreads();
    for (int off = 1; off < 1024; off <<= 1) {
        int t = (tid >= off) ? s[tid - off] : 0;
        __syncthreads();
        s[tid] += t;
        __syncthreads();
    }
    if (tid < nblk) blockoff[tid] = s[tid] - v;  // exclusive
    if (tid == 1023) row_start[n] = s[1023];
}

__global__ __launch_bounds__(256) void scan_final_kernel(
    const int* __restrict__ cnt, const int* __restrict__ blockoff,
    int* __restrict__ row_start, int n) {
    __shared__ int s[256];
    const int tid = threadIdx.x;
    int i = blockIdx.x * 256 + tid;
    int v = (i < n) ? cnt[i] : 0;
    s[tid] = v;
    __syncthreads();
    for (int off = 1; off < 256; off <<= 1) {
        int t = (tid >= off) ? s[tid - off] : 0;
        __syncthreads();
        s[tid] += t;
        __syncthreads();
    }
    if (i < n) row_start[i] = blockoff[blockIdx.x] + s[tid] - v;
}

__global__ void fill_kernel(const int* __restrict__ src,
                            const int* __restrict__ dst,
                            const int* __restrict__ row_start,
                            int* __restrict__ cnt,  // consumed as cursor
                            int* __restrict__ edge_src, int n_edges) {
    int e = blockIdx.x * blockDim.x + threadIdx.x;
    if (e < n_edges) {
        int d = dst[e];
        int pos = row_start[d] + atomicSub(&cnt[d], 1) - 1;
        edge_src[pos] = src[e];
    }
}

// ---------------------------------------------------------------------------
// mean aggregation over bf16 rows: one wave per node, 2 cols/lane (4B/lane,
// 256B coalesced per row), f32 accumulate, bf16 out, 4-deep load ILP.
// ---------------------------------------------------------------------------
__global__ __launch_bounds__(256) void aggregate_kernel(
    const unsigned short* __restrict__ Xbf, const int* __restrict__ row_start,
    const int* __restrict__ edge_src, unsigned short* __restrict__ Mbf,
    int n_nodes) {
    const int wave = (blockIdx.x * blockDim.x + threadIdx.x) >> 6;
    const int lane = threadIdx.x & 63;
    if (wave >= n_nodes) return;
    const int beg = row_start[wave];
    const int end = row_start[wave + 1];
    float a0 = 0.f, a1 = 0.f, b0 = 0.f, b1 = 0.f;
    float c0 = 0.f, c1 = 0.f, d0 = 0.f, d1 = 0.f;
    int i = beg;
    for (; i + 3 < end; i += 4) {
        int s0 = edge_src[i];
        int s1 = edge_src[i + 1];
        int s2 = edge_src[i + 2];
        int s3 = edge_src[i + 3];
        unsigned int v0 =
            reinterpret_cast<const unsigned int*>(Xbf + (size_t)s0 * NFEAT)[lane];
        unsigned int v1 =
            reinterpret_cast<const unsigned int*>(Xbf + (size_t)s1 * NFEAT)[lane];
        unsigned int v2 =
            reinterpret_cast<const unsigned int*>(Xbf + (size_t)s2 * NFEAT)[lane];
        unsigned int v3 =
            reinterpret_cast<const unsigned int*>(Xbf + (size_t)s3 * NFEAT)[lane];
        a0 += bflo(v0); a1 += bfhi(v0);
        b0 += bflo(v1); b1 += bfhi(v1);
        c0 += bflo(v2); c1 += bfhi(v2);
        d0 += bflo(v3); d1 += bfhi(v3);
    }
    for (; i < end; ++i) {
        int s0 = edge_src[i];
        unsigned int v0 =
            reinterpret_cast<const unsigned int*>(Xbf + (size_t)s0 * NFEAT)[lane];
        a0 += bflo(v0); a1 += bfhi(v0);
    }
    const float inv = 1.0f / fmaxf((float)(end - beg), 1.0f);
    reinterpret_cast<unsigned int*>(Mbf + (size_t)wave * NFEAT)[lane] =
        pack2bf((a0 + b0 + c0 + d0) * inv, (a1 + b1 + c1 + d1) * inv);
}

// ---------------------------------------------------------------------------
// MFMA GEMM: out = [relu]( [Xbf | Mbf] @ WcT^T + b ),  K=256, 16x16x32 bf16.
// Block: 512 thr = 8 waves; wave w owns rows [blk*128 + w*16, +16) x all 128
// cols. Full weight layer (64KB) staged in LDS with 16B-chunk XOR swizzle
// (chunk' = chunk ^ (row&7)) -> B ds_read_b128 is 2-way/bank = conflict-free.
// A-fragments (own rows) hoisted to registers. 2 blocks/CU (LDS-limited).
// In-place out_bf==Xbf is safe: each wave writes only rows it alone read.
// ---------------------------------------------------------------------------
__global__ __launch_bounds__(512, 4) void mfma_gemm_kernel(
    const unsigned short* __restrict__ Xbf,  // [N,128] bf16
    const unsigned short* __restrict__ Mbf,  // [N,128] bf16
    const unsigned short* __restrict__ WcT,  // [128][256] bf16 (j-major)
    const float* __restrict__ bias,          // [128] f32
    unsigned short* out_bf,                  // bf16 out (or null)
    float* out_f32,                          // f32 out (or null)
    int n_nodes, int do_relu) {
    __shared__ unsigned short sW[128 * 256];  // 64 KB, swizzled

    const int tid = threadIdx.x;
    const int wave = tid >> 6;
    const int lane = tid & 63;

    // ---- stage WcT -> LDS (coalesced global read, swizzled ds_write) ----
#pragma unroll
    for (int it = 0; it < 8; ++it) {
        int c = it * 512 + tid;        // 16B-chunk id, 4096 total
        int row = c >> 5;              // 0..127
        int ch = c & 31;               // chunk within row
        bf16x8 v = *reinterpret_cast<const bf16x8*>(WcT + row * 256 + ch * 8);
        *reinterpret_cast<bf16x8*>(sW + row * 256 + ((ch ^ (row & 7)) << 3)) = v;
    }

    const int row_base = blockIdx.x * 128 + wave * 16;
    const int l15 = lane & 15;
    const int g = lane >> 4;       // 0..3
    const int kgrp = g * 8;        // k-offset within 32-wide k-step

    // ---- hoist A fragments (this wave's 16 rows, k=0..255) ----
    const int arow = min(row_base + l15, n_nodes - 1);
    const unsigned short* Arow = Xbf + (size_t)arow * NFEAT;
    const unsigned short* Mrow = Mbf + (size_t)arow * NFEAT;
    bf16x8 afr[8];
#pragma unroll
    for (int s = 0; s < 4; ++s)
        afr[s] = *reinterpret_cast<const bf16x8*>(Arow + s * 32 + kgrp);
#pragma unroll
    for (int s = 0; s < 4; ++s)
        afr[4 + s] = *reinterpret_cast<const bf16x8*>(Mrow + s * 32 + kgrp);

    f32x4 acc[8];
#pragma unroll
    for (int t = 0; t < 8; ++t) acc[t] = (f32x4){0.f, 0.f, 0.f, 0.f};

    __syncthreads();  // sW ready

#pragma unroll
    for (int ks = 0; ks < 8; ++ks) {  // k0 = ks*32
        const int chunk_w = ks * 4 + g;  // (k0 + kgrp)/8
#pragma unroll
        for (int t = 0; t < 8; ++t) {
            const int j = t * 16 + l15;
            bf16x8 b = *reinterpret_cast<const bf16x8*>(
                sW + j * 256 + ((chunk_w ^ (j & 7)) << 3));
            acc[t] =
                __builtin_amdgcn_mfma_f32_16x16x32_bf16(afr[ks], b, acc[t], 0, 0, 0);
        }
    }

    // C/D layout: col = lane&15, row = (lane>>4)*4 + reg
    const int crow0 = row_base + g * 4;
#pragma unroll
    for (int t = 0; t < 8; ++t) {
        const int c = t * 16 + l15;
        const float bj = bias[c];
#pragma unroll
        for (int r = 0; r < 4; ++r) {
            const int gr = crow0 + r;
            if (gr < n_nodes) {
                float v = acc[t][r] + bj;
                if (do_relu) v = fmaxf(v, 0.f);
                if (out_f32)
                    out_f32[(size_t)gr * NFEAT + c] = v;
                else
                    out_bf[(size_t)gr * NFEAT + c] = f2bf(v);
            }
        }
    }
}

extern "C" void kernel_launch(void* const* d_in, const int* in_sizes, int n_in,
                              void* d_out, int out_size, void* d_ws,
                              size_t ws_size, hipStream_t stream) {
    const float* h = (const float*)d_in[0];
    const int* src = (const int*)d_in[1];
    const int* dst = (const int*)d_in[2];
    const float* Ws0 = (const float*)d_in[3];
    const float* Wn0 = (const float*)d_in[4];
    const float* b0 = (const float*)d_in[5];
    const float* Ws1 = (const float*)d_in[6];
    const float* Wn1 = (const float*)d_in[7];
    const float* b1 = (const float*)d_in[8];
    float* out = (float*)d_out;

    const int n_nodes = in_sizes[0] / NFEAT;
    const int n_edges = in_sizes[1];
    const int nblk = (n_nodes + 255) / 256;  // scan blocks (<=1024)

    // workspace layout (~28.5 MB)
    unsigned short* hbf = (unsigned short*)d_ws;          // [N,128] bf16 (+h1)
    unsigned short* Mbf = hbf + (size_t)n_nodes * NFEAT;  // [N,128] bf16
    unsigned short* WcT = Mbf + (size_t)n_nodes * NFEAT;  // 2*[128][256] bf16
    int* row_start = (int*)(WcT + 2 * 128 * 256);         // [N+1]
    int* cnt = row_start + (n_nodes + 1);                 // [N]
    int* edge_src = cnt + n_nodes;                        // [E]
    // scan scratch aliases Mbf (dead until aggregate, which runs after CSR)
    int* blocksum = (int*)Mbf;        // [nblk]
    int* blockoff = blocksum + nblk;  // [nblk]

    // prep: weights + bf16 activations + CSR
    zero_kernel<<<(n_nodes + 255) / 256, 256, 0, stream>>>(cnt, n_nodes);
    prep_weights_kernel<<<(2 * 128 * 256 + 255) / 256, 256, 0, stream>>>(
        Ws0, Wn0, Ws1, Wn1, WcT);
    convert_kernel<<<(n_nodes * NFEAT / 4 + 255) / 256, 256, 0, stream>>>(
        h, hbf, n_nodes * NFEAT / 4);
    hist_kernel<<<(n_edges + 255) / 256, 256, 0, stream>>>(dst, cnt, n_edges);
    scan_blocksum_kernel<<<nblk, 256, 0, stream>>>(cnt, blocksum, n_nodes);
    scan_blockoff_kernel<<<1, 1024, 0, stream>>>(blocksum, blockoff, row_start,
                                                 nblk, n_nodes);
    scan_final_kernel<<<nblk, 256, 0, stream>>>(cnt, blockoff, row_start,
                                                n_nodes);
    fill_kernel<<<(n_edges + 255) / 256, 256, 0, stream>>>(
        src, dst, row_start, cnt, edge_src, n_edges);

    const int agg_blocks = (n_nodes * 64 + 255) / 256;
    const int gemm_blocks = (n_nodes + 127) / 128;

    // ---- layer 0 (h1 bf16 written in-place over hbf) ----
    aggregate_kernel<<<agg_blocks, 256, 0, stream>>>(hbf, row_start, edge_src,
                                                     Mbf, n_nodes);
    mfma_gemm_kernel<<<gemm_blocks, 512, 0, stream>>>(
        hbf, Mbf, WcT, b0, hbf, (float*)nullptr, n_nodes, 1);

    // ---- layer 1 (f32 out to d_out) ----
    aggregate_kernel<<<agg_blocks, 256, 0, stream>>>(hbf, row_start, edge_src,
                                                     Mbf, n_nodes);
    mfma_gemm_kernel<<<gemm_blocks, 512, 0, stream>>>(
        hbf, Mbf, WcT + 32768, b1, (unsigned short*)nullptr, out, n_nodes, 0);
}

// Round 6
// 167.226 us; speedup vs baseline: 14.5761x; 1.0761x over previous
//
#include <hip/hip_runtime.h>
#include <hip/hip_bf16.h>

#define NFEAT 128

typedef __attribute__((ext_vector_type(8))) short bf16x8;
typedef __attribute__((ext_vector_type(4))) float f32x4;

__device__ inline unsigned short f2bf(float f) {  // RNE f32 -> bf16
    unsigned int u = __float_as_uint(f);
    u += 0x7fffu + ((u >> 16) & 1u);
    return (unsigned short)(u >> 16);
}
__device__ inline unsigned int pack2bf(float lo, float hi) {
    return (unsigned int)f2bf(lo) | ((unsigned int)f2bf(hi) << 16);
}
__device__ inline float bf2f(unsigned short s) {
    return __uint_as_float(((unsigned int)s) << 16);
}

// ---------------------------------------------------------------------------
// fused prep: convert h->bf16  |  pack+transpose weights  |  zero cnt
// ---------------------------------------------------------------------------
__global__ void prep_kernel(const float* __restrict__ h,
                            const float* __restrict__ Ws0,
                            const float* __restrict__ Wn0,
                            const float* __restrict__ Ws1,
                            const float* __restrict__ Wn1,
                            unsigned short* __restrict__ hbf,
                            unsigned short* __restrict__ WcT,
                            int* __restrict__ cnt, int n4, int nw, int nn) {
    int i = blockIdx.x * blockDim.x + threadIdx.x;
    if (i < n4) {  // convert 4 f32 -> 4 bf16
        float4 v = reinterpret_cast<const float4*>(h)[i];
        uint2 o;
        o.x = pack2bf(v.x, v.y);
        o.y = pack2bf(v.z, v.w);
        reinterpret_cast<uint2*>(hbf)[i] = o;
    } else if (i < n4 + nw) {  // weights: WcT[layer][j][k]
        int idx = i - n4;
        int layer = idx >> 15;
        int rem = idx & 32767;
        int j = rem >> 8;
        int k = rem & 255;
        const float* Ws = layer ? Ws1 : Ws0;
        const float* Wn = layer ? Wn1 : Wn0;
        float v = (k < 128) ? Ws[k * 128 + j] : Wn[(k - 128) * 128 + j];
        WcT[layer * 32768 + j * 256 + k] = f2bf(v);
    } else if (i < n4 + nw + nn) {
        cnt[i - n4 - nw] = 0;
    }
}

// ---------------------------------------------------------------------------
// CSR build: histogram -> hierarchical scan (A,B,C) -> fill
// ---------------------------------------------------------------------------
__global__ void hist_kernel(const int* __restrict__ dst, int* __restrict__ cnt,
                            int n_edges) {
    int e = blockIdx.x * blockDim.x + threadIdx.x;
    if (e < n_edges) atomicAdd(&cnt[dst[e]], 1);
}

__global__ __launch_bounds__(256) void scan_blocksum_kernel(
    const int* __restrict__ cnt, int* __restrict__ blocksum, int n) {
    __shared__ int s[256];
    int i = blockIdx.x * 256 + threadIdx.x;
    s[threadIdx.x] = (i < n) ? cnt[i] : 0;
    __syncthreads();
    for (int off = 128; off > 0; off >>= 1) {
        if (threadIdx.x < off) s[threadIdx.x] += s[threadIdx.x + off];
        __syncthreads();
    }
    if (threadIdx.x == 0) blocksum[blockIdx.x] = s[0];
}

__global__ __launch_bounds__(1024) void scan_blockoff_kernel(
    const int* __restrict__ blocksum, int* __restrict__ blockoff,
    int* __restrict__ row_start, int nblk, int n) {
    __shared__ int s[1024];
    const int tid = threadIdx.x;
    int v = (tid < nblk) ? blocksum[tid] : 0;
    s[tid] = v;
    __syncthreads();
    for (int off = 1; off < 1024; off <<= 1) {
        int t = (tid >= off) ? s[tid - off] : 0;
        __syncthreads();
        s[tid] += t;
        __syncthreads();
    }
    if (tid < nblk) blockoff[tid] = s[tid] - v;  // exclusive
    if (tid == 1023) row_start[n] = s[1023];
}

__global__ __launch_bounds__(256) void scan_final_kernel(
    const int* __restrict__ cnt, const int* __restrict__ blockoff,
    int* __restrict__ row_start, int n) {
    __shared__ int s[256];
    const int tid = threadIdx.x;
    int i = blockIdx.x * 256 + tid;
    int v = (i < n) ? cnt[i] : 0;
    s[tid] = v;
    __syncthreads();
    for (int off = 1; off < 256; off <<= 1) {
        int t = (tid >= off) ? s[tid - off] : 0;
        __syncthreads();
        s[tid] += t;
        __syncthreads();
    }
    if (i < n) row_start[i] = blockoff[blockIdx.x] + s[tid] - v;
}

__global__ void fill_kernel(const int* __restrict__ src,
                            const int* __restrict__ dst,
                            const int* __restrict__ row_start,
                            int* __restrict__ cnt,  // consumed as cursor
                            int* __restrict__ edge_src, int n_edges) {
    int e = blockIdx.x * blockDim.x + threadIdx.x;
    if (e < n_edges) {
        int d = dst[e];
        int pos = row_start[d] + atomicSub(&cnt[d], 1) - 1;
        edge_src[pos] = src[e];
    }
}

// ---------------------------------------------------------------------------
// mean aggregation, high-MLP form: one wave per node; quarter-wave per row.
// lane = (sub = l>>4, chunk = l&15): 4 rows loaded simultaneously (16 lanes x
// 16B each), unrolled 4x -> 16 rows in flight per wave. Rows of one node sum
// into 8 f32/lane; final 2-step shfl_xor(16,32) reduce; sub==0 lanes write
// the 256B bf16 row.
// ---------------------------------------------------------------------------
__global__ __launch_bounds__(256) void aggregate_kernel(
    const unsigned short* __restrict__ Xbf, const int* __restrict__ row_start,
    const int* __restrict__ edge_src, unsigned short* __restrict__ Mbf,
    int n_nodes) {
    const int wave = (blockIdx.x * blockDim.x + threadIdx.x) >> 6;
    const int lane = threadIdx.x & 63;
    if (wave >= n_nodes) return;
    const int beg = row_start[wave];
    const int end = row_start[wave + 1];
    const int sub = lane >> 4;   // 0..3: row group
    const int c16 = lane & 15;   // 16B chunk within row

    float a[8];
#pragma unroll
    for (int t = 0; t < 8; ++t) a[t] = 0.f;

    for (int ibase = beg; ibase < end; ibase += 16) {
#pragma unroll
        for (int j = 0; j < 4; ++j) {
            const int e = ibase + j * 4 + sub;
            bf16x8 v = {};
            if (e < end) {
                v = *reinterpret_cast<const bf16x8*>(
                    Xbf + (size_t)edge_src[e] * NFEAT + c16 * 8);
            }
#pragma unroll
            for (int t = 0; t < 8; ++t) a[t] += bf2f((unsigned short)v[t]);
        }
    }

    // reduce across the 4 row-groups (lanes l, l^16, l^32, l^48)
#pragma unroll
    for (int t = 0; t < 8; ++t) {
        float x = a[t];
        x += __shfl_xor(x, 16, 64);
        x += __shfl_xor(x, 32, 64);
        a[t] = x;
    }

    if (sub == 0) {
        const float inv = 1.0f / fmaxf((float)(end - beg), 1.0f);
        uint4 o;
        o.x = pack2bf(a[0] * inv, a[1] * inv);
        o.y = pack2bf(a[2] * inv, a[3] * inv);
        o.z = pack2bf(a[4] * inv, a[5] * inv);
        o.w = pack2bf(a[6] * inv, a[7] * inv);
        reinterpret_cast<uint4*>(Mbf + (size_t)wave * NFEAT)[c16] = o;
    }
}

// ---------------------------------------------------------------------------
// MFMA GEMM: out = [relu]( [Xbf | Mbf] @ WcT^T + b ),  K=256, 16x16x32 bf16.
// Block: 512 thr = 8 waves; wave w owns rows [blk*128 + w*16, +16) x all 128
// cols. Full weight layer (64KB) staged in LDS with 16B-chunk XOR swizzle
// (chunk' = chunk ^ (row&7)) -> B ds_read_b128 is 2-way/bank = conflict-free.
// A-fragments (own rows) hoisted to registers. 2 blocks/CU (LDS-limited).
// In-place out_bf==Xbf is safe: each wave writes only rows it alone read.
// ---------------------------------------------------------------------------
__global__ __launch_bounds__(512, 4) void mfma_gemm_kernel(
    const unsigned short* __restrict__ Xbf,  // [N,128] bf16
    const unsigned short* __restrict__ Mbf,  // [N,128] bf16
    const unsigned short* __restrict__ WcT,  // [128][256] bf16 (j-major)
    const float* __restrict__ bias,          // [128] f32
    unsigned short* out_bf,                  // bf16 out (or null)
    float* out_f32,                          // f32 out (or null)
    int n_nodes, int do_relu) {
    __shared__ unsigned short sW[128 * 256];  // 64 KB, swizzled

    const int tid = threadIdx.x;
    const int wave = tid >> 6;
    const int lane = tid & 63;

    // ---- stage WcT -> LDS (coalesced global read, swizzled ds_write) ----
#pragma unroll
    for (int it = 0; it < 8; ++it) {
        int c = it * 512 + tid;        // 16B-chunk id, 4096 total
        int row = c >> 5;              // 0..127
        int ch = c & 31;               // chunk within row
        bf16x8 v = *reinterpret_cast<const bf16x8*>(WcT + row * 256 + ch * 8);
        *reinterpret_cast<bf16x8*>(sW + row * 256 + ((ch ^ (row & 7)) << 3)) = v;
    }

    const int row_base = blockIdx.x * 128 + wave * 16;
    const int l15 = lane & 15;
    const int g = lane >> 4;       // 0..3
    const int kgrp = g * 8;        // k-offset within 32-wide k-step

    // ---- hoist A fragments (this wave's 16 rows, k=0..255) ----
    const int arow = min(row_base + l15, n_nodes - 1);
    const unsigned short* Arow = Xbf + (size_t)arow * NFEAT;
    const unsigned short* Mrow = Mbf + (size_t)arow * NFEAT;
    bf16x8 afr[8];
#pragma unroll
    for (int s = 0; s < 4; ++s)
        afr[s] = *reinterpret_cast<const bf16x8*>(Arow + s * 32 + kgrp);
#pragma unroll
    for (int s = 0; s < 4; ++s)
        afr[4 + s] = *reinterpret_cast<const bf16x8*>(Mrow + s * 32 + kgrp);

    f32x4 acc[8];
#pragma unroll
    for (int t = 0; t < 8; ++t) acc[t] = (f32x4){0.f, 0.f, 0.f, 0.f};

    __syncthreads();  // sW ready

#pragma unroll
    for (int ks = 0; ks < 8; ++ks) {  // k0 = ks*32
        const int chunk_w = ks * 4 + g;  // (k0 + kgrp)/8
#pragma unroll
        for (int t = 0; t < 8; ++t) {
            const int j = t * 16 + l15;
            bf16x8 b = *reinterpret_cast<const bf16x8*>(
                sW + j * 256 + ((chunk_w ^ (j & 7)) << 3));
            acc[t] =
                __builtin_amdgcn_mfma_f32_16x16x32_bf16(afr[ks], b, acc[t], 0, 0, 0);
        }
    }

    // C/D layout: col = lane&15, row = (lane>>4)*4 + reg
    const int crow0 = row_base + g * 4;
#pragma unroll
    for (int t = 0; t < 8; ++t) {
        const int c = t * 16 + l15;
        const float bj = bias[c];
#pragma unroll
        for (int r = 0; r < 4; ++r) {
            const int gr = crow0 + r;
            if (gr < n_nodes) {
                float v = acc[t][r] + bj;
                if (do_relu) v = fmaxf(v, 0.f);
                if (out_f32)
                    out_f32[(size_t)gr * NFEAT + c] = v;
                else
                    out_bf[(size_t)gr * NFEAT + c] = f2bf(v);
            }
        }
    }
}

extern "C" void kernel_launch(void* const* d_in, const int* in_sizes, int n_in,
                              void* d_out, int out_size, void* d_ws,
                              size_t ws_size, hipStream_t stream) {
    const float* h = (const float*)d_in[0];
    const int* src = (const int*)d_in[1];
    const int* dst = (const int*)d_in[2];
    const float* Ws0 = (const float*)d_in[3];
    const float* Wn0 = (const float*)d_in[4];
    const float* b0 = (const float*)d_in[5];
    const float* Ws1 = (const float*)d_in[6];
    const float* Wn1 = (const float*)d_in[7];
    const float* b1 = (const float*)d_in[8];
    float* out = (float*)d_out;

    const int n_nodes = in_sizes[0] / NFEAT;
    const int n_edges = in_sizes[1];
    const int nblk = (n_nodes + 255) / 256;  // scan blocks (<=1024)

    // workspace layout (~28.5 MB)
    unsigned short* hbf = (unsigned short*)d_ws;          // [N,128] bf16 (+h1)
    unsigned short* Mbf = hbf + (size_t)n_nodes * NFEAT;  // [N,128] bf16
    unsigned short* WcT = Mbf + (size_t)n_nodes * NFEAT;  // 2*[128][256] bf16
    int* row_start = (int*)(WcT + 2 * 128 * 256);         // [N+1]
    int* cnt = row_start + (n_nodes + 1);                 // [N]
    int* edge_src = cnt + n_nodes;                        // [E]
    // scan scratch aliases Mbf (dead until aggregate, which runs after CSR)
    int* blocksum = (int*)Mbf;        // [nblk]
    int* blockoff = blocksum + nblk;  // [nblk]

    // ---- fused prep (convert + weights + zero cnt) ----
    const int n4 = n_nodes * NFEAT / 4;
    const int nw = 2 * 128 * 256;
    const int prep_total = n4 + nw + n_nodes;
    prep_kernel<<<(prep_total + 255) / 256, 256, 0, stream>>>(
        h, Ws0, Wn0, Ws1, Wn1, hbf, WcT, cnt, n4, nw, n_nodes);

    // ---- CSR build ----
    hist_kernel<<<(n_edges + 255) / 256, 256, 0, stream>>>(dst, cnt, n_edges);
    scan_blocksum_kernel<<<nblk, 256, 0, stream>>>(cnt, blocksum, n_nodes);
    scan_blockoff_kernel<<<1, 1024, 0, stream>>>(blocksum, blockoff, row_start,
                                                 nblk, n_nodes);
    scan_final_kernel<<<nblk, 256, 0, stream>>>(cnt, blockoff, row_start,
                                                n_nodes);
    fill_kernel<<<(n_edges + 255) / 256, 256, 0, stream>>>(
        src, dst, row_start, cnt, edge_src, n_edges);

    const int agg_blocks = (n_nodes * 64 + 255) / 256;
    const int gemm_blocks = (n_nodes + 127) / 128;

    // ---- layer 0 (h1 bf16 written in-place over hbf) ----
    aggregate_kernel<<<agg_blocks, 256, 0, stream>>>(hbf, row_start, edge_src,
                                                     Mbf, n_nodes);
    mfma_gemm_kernel<<<gemm_blocks, 512, 0, stream>>>(
        hbf, Mbf, WcT, b0, hbf, (float*)nullptr, n_nodes, 1);

    // ---- layer 1 (f32 out to d_out) ----
    aggregate_kernel<<<agg_blocks, 256, 0, stream>>>(hbf, row_start, edge_src,
                                                     Mbf, n_nodes);
    mfma_gemm_kernel<<<gemm_blocks, 512, 0, stream>>>(
        hbf, Mbf, WcT + 32768, b1, (unsigned short*)nullptr, out, n_nodes, 0);
}